// Round 10
// baseline (521.439 us; speedup 1.0000x reference)
//
#include <hip/hip_runtime.h>
#include <hip/hip_fp16.h>

#define NUM_USERS 100000
#define NUM_ITEMS 50000
#define NTOT (NUM_USERS + NUM_ITEMS)
#define EMBED_DIM 64
#define NNZ_E 4800000
#define NUM_LAYERS 3

#define ROWS_PER_BUCKET 256
#define NBUCK ((NTOT + ROWS_PER_BUCKET - 1) / ROWS_PER_BUCKET)   // 586
#define BCAP 8960                   // bucket mean 8191 + 8.5 sigma
#define NSUPER 37                   // src >> 12 : 4096 rows per super
#define SCAP 134144                 // super mean 131072 + 8.5 sigma (357)
#define EPB1 4096                   // edges per block, pass 1 (1172 blocks)
#define EPB2 4096                   // edges per block, pass 2
#define DMASK 0x3FFFF               // 18 bits for dst (< 150000 < 2^18)

// ---------------- init: b0(fp16) = concat(user_emb, item_emb) ----------------
__global__ void __launch_bounds__(256)
k_init(const float* __restrict__ ue, const float* __restrict__ ie,
       __half* __restrict__ b0) {
    const long long total2 = (long long)NTOT * EMBED_DIM / 2;
    const long long u2 = (long long)NUM_USERS * EMBED_DIM / 2;
    const float2* ue2 = (const float2*)ue;
    const float2* ie2 = (const float2*)ie;
    __half2* b02 = (__half2*)b0;
    for (long long i = (long long)blockIdx.x * blockDim.x + threadIdx.x;
         i < total2; i += (long long)gridDim.x * blockDim.x) {
        float2 v = (i < u2) ? ue2[i] : ie2[i - u2];
        b02[i] = __floats2half2_rn(v.x, v.y);
    }
}

// ---------------- radix pass 1: bin into 37 supers (885 B runs) --------------
__global__ void __launch_bounds__(256)
k_super(const int* __restrict__ src, const int* __restrict__ dst,
        const float* __restrict__ val, int* __restrict__ cursorS,
        int2* __restrict__ outS) {
    __shared__ int h[NSUPER];
    __shared__ int base[NSUPER];
    int t = threadIdx.x;
    if (t < NSUPER) h[t] = 0;
    __syncthreads();
    long long e0 = (long long)blockIdx.x * EPB1;
    int n = (int)(((long long)NNZ_E - e0) < EPB1 ? (NNZ_E - e0) : EPB1);
    for (int i = t; i < n; i += 256) {
        int s = __builtin_nontemporal_load(&src[e0 + i]);
        atomicAdd(&h[s >> 12], 1);
    }
    __syncthreads();
    if (t < NSUPER) {
        int c = h[t];
        base[t] = (c > 0) ? atomicAdd(&cursorS[t], c) : 0;
        h[t] = 0;
    }
    __syncthreads();
    for (int i = t; i < n; i += 256) {
        int s = __builtin_nontemporal_load(&src[e0 + i]);
        int d = __builtin_nontemporal_load(&dst[e0 + i]);
        float v = __builtin_nontemporal_load(&val[e0 + i]);
        int sb = s >> 12;
        int off = base[sb] + atomicAdd(&h[sb], 1);
        outS[(long long)sb * SCAP + off] =
            make_int2(d | ((s & 4095) << 18), __float_as_int(v));  // 18b dst | 12b row
    }
}

// ---------------- radix pass 2: super -> 16 buckets (2 KB runs) --------------
__global__ void __launch_bounds__(256)
k_bin(const int2* __restrict__ superA, const int* __restrict__ cursorS,
      int* __restrict__ cursorB, int2* __restrict__ outB) {
    __shared__ int h[16];
    __shared__ int base16[16];
    int s = blockIdx.y;
    int cnt = cursorS[s];
    int beg = blockIdx.x * EPB2;
    if (beg >= cnt) return;
    int n = (cnt - beg < EPB2) ? (cnt - beg) : EPB2;
    int t = threadIdx.x;
    const long long* in8 = (const long long*)(superA + (long long)s * SCAP + beg);
    if (t < 16) h[t] = 0;
    __syncthreads();
    for (int i = t; i < n; i += 256) {
        long long raw = __builtin_nontemporal_load(&in8[i]);
        int row12 = ((int)raw >> 18) & 4095;
        atomicAdd(&h[row12 >> 8], 1);
    }
    __syncthreads();
    if (t < 16) {
        int c = h[t];
        base16[t] = (c > 0) ? atomicAdd(&cursorB[s * 16 + t], c) : 0;
        h[t] = 0;
    }
    __syncthreads();
    for (int i = t; i < n; i += 256) {
        long long raw = __builtin_nontemporal_load(&in8[i]);
        int ex = (int)raw;
        int row12 = (ex >> 18) & 4095;
        int bl = row12 >> 8;
        int off = base16[bl] + atomicAdd(&h[bl], 1);
        outB[(long long)(s * 16 + bl) * BCAP + off] =
            make_int2((ex & DMASK) | ((row12 & 255) << 18), (int)(raw >> 32));
    }
}

// -------- fallback single-pass bucket scatter (if ws too small) --------------
__global__ void __launch_bounds__(256)
k_bucket(const int* __restrict__ src, const int* __restrict__ dst,
         const float* __restrict__ val, int* __restrict__ cursor,
         int2* __restrict__ outA) {
    __shared__ int h[NBUCK];
    __shared__ int base[NBUCK];
    for (int i = threadIdx.x; i < NBUCK; i += 256) h[i] = 0;
    __syncthreads();
    long long e0 = (long long)blockIdx.x * EPB1;
    int n = (int)(((long long)NNZ_E - e0) < EPB1 ? (NNZ_E - e0) : EPB1);
    for (int i = threadIdx.x; i < n; i += 256) {
        int s = __builtin_nontemporal_load(&src[e0 + i]);
        atomicAdd(&h[s >> 8], 1);
    }
    __syncthreads();
    for (int i = threadIdx.x; i < NBUCK; i += 256) {
        int c = h[i];
        base[i] = (c > 0) ? atomicAdd(&cursor[i], c) : 0;
        h[i] = 0;
    }
    __syncthreads();
    for (int i = threadIdx.x; i < n; i += 256) {
        int s = __builtin_nontemporal_load(&src[e0 + i]);
        int d = __builtin_nontemporal_load(&dst[e0 + i]);
        float v = __builtin_nontemporal_load(&val[e0 + i]);
        int b = s >> 8;
        int off = base[b] + atomicAdd(&h[b], 1);
        outA[(long long)b * BCAP + off] =
            make_int2(d | ((s & 255) << 18), __float_as_int(v));
    }
}

// ---------------- phase 3: per-bucket LDS counting sort -> row-grouped ------
__global__ void __launch_bounds__(256)
k_sortbucket(const int2* __restrict__ inAll, const int* __restrict__ cursor,
             int2* __restrict__ outB, int2* __restrict__ rp) {
    __shared__ int h[ROWS_PER_BUCKET];
    __shared__ int excl[ROWS_PER_BUCKET];
    __shared__ int cur[ROWS_PER_BUCKET];
    int b = blockIdx.x;
    int t = threadIdx.x;
    int cnt = cursor[b];
    const long long* in8 = (const long long*)(inAll + (long long)b * BCAP);
    h[t] = 0;
    __syncthreads();
    for (int i = t; i < cnt; i += 256) {
        long long raw = __builtin_nontemporal_load(&in8[i]);
        atomicAdd(&h[((int)raw >> 18) & 255], 1);
    }
    __syncthreads();
    int v = h[t];
    excl[t] = v;
    __syncthreads();
    for (int off = 1; off < 256; off <<= 1) {
        int x = (t >= off) ? excl[t - off] : 0;
        __syncthreads();
        excl[t] += x;
        __syncthreads();
    }
    int myExcl = excl[t] - v;
    cur[t] = myExcl;
    long long gb = (long long)b * BCAP;
    int row = b * ROWS_PER_BUCKET + t;
    if (row < NTOT) rp[row] = make_int2((int)(gb + myExcl), (int)(gb + myExcl + v));
    __syncthreads();
    for (int i = t; i < cnt; i += 256) {
        long long raw = __builtin_nontemporal_load(&in8[i]);
        int ex = (int)raw;
        int r = (ex >> 18) & 255;
        int slot = atomicAdd(&cur[r], 1);
        outB[gb + slot] = make_int2(ex, (int)(raw >> 32));
    }
}

// ---- CSR SpMM (round-6 form): one wave per row, half2 gather, 8-wide -------
// LAST layer fuses the final average: out = (ego0 + b1 + b2 + acc) / 4.
template <bool LAST>
__global__ void __launch_bounds__(256)
k_spmm_csr(const int2* __restrict__ edges, const int2* __restrict__ rp,
           const __half* __restrict__ x, __half* __restrict__ nxt,
           const float* __restrict__ ue, const float* __restrict__ ie,
           const __half* __restrict__ b1, const __half* __restrict__ b2,
           float* __restrict__ out) {
    int row = blockIdx.x * 4 + (threadIdx.x >> 6);
    int lane = threadIdx.x & 63;
    if (row >= NTOT) return;
    int2 be = rp[row];
    int beg = be.x;
    int end = be.y;
    int sub = lane >> 5;
    int l2 = lane & 31;
    const __half2* x2 = (const __half2*)x;   // row stride 32 half2
    float accx = 0.f, accy = 0.f;
    int j = beg;
    for (; j + 16 <= end; j += 16) {
        int2 e[8];
        __half2 xv[8];
#pragma unroll
        for (int k = 0; k < 8; ++k) e[k] = edges[j + sub * 8 + k];
#pragma unroll
        for (int k = 0; k < 8; ++k)
            xv[k] = x2[(long long)(e[k].x & DMASK) * 32 + l2];
#pragma unroll
        for (int k = 0; k < 8; ++k) {
            float w = __int_as_float(e[k].y);
            float2 xf = __half22float2(xv[k]);
            accx = fmaf(w, xf.x, accx);
            accy = fmaf(w, xf.y, accy);
        }
    }
    for (int t2 = j + sub; t2 < end; t2 += 2) {
        int2 e = edges[t2];
        float w = __int_as_float(e.y);
        float2 xf = __half22float2(x2[(long long)(e.x & DMASK) * 32 + l2]);
        accx = fmaf(w, xf.x, accx);
        accy = fmaf(w, xf.y, accy);
    }
    accx += __shfl_xor(accx, 32);
    accy += __shfl_xor(accy, 32);
    if (sub == 0) {
        if (!LAST) {
            ((__half2*)nxt)[(long long)row * 32 + l2] = __floats2half2_rn(accx, accy);
        } else {
            const float2* ego2 = (row < NUM_USERS)
                ? (const float2*)(ue + (long long)row * EMBED_DIM)
                : (const float2*)(ie + (long long)(row - NUM_USERS) * EMBED_DIM);
            float2 v = ego2[l2];
            float2 a = __half22float2(((const __half2*)b1)[(long long)row * 32 + l2]);
            float2 bb = __half22float2(((const __half2*)b2)[(long long)row * 32 + l2]);
            const float s = 1.0f / (NUM_LAYERS + 1);
            float2 r;
            r.x = (v.x + a.x + bb.x + accx) * s;
            r.y = (v.y + a.y + bb.y + accy) * s;
            ((float2*)out)[(long long)row * 32 + l2] = r;
        }
    }
}

extern "C" void kernel_launch(void* const* d_in, const int* in_sizes, int n_in,
                              void* d_out, int out_size, void* d_ws, size_t ws_size,
                              hipStream_t stream) {
    const float* user_emb = (const float*)d_in[0];
    const float* item_emb = (const float*)d_in[1];
    const int* edge_src   = (const int*)d_in[2];
    const int* edge_dst   = (const int*)d_in[3];
    const float* edge_val = (const float*)d_in[4];
    float* out = (float*)d_out;

    const size_t halfMat  = (size_t)NTOT * EMBED_DIM * sizeof(__half);  // 19.2 MB
    const size_t buckBytes = (size_t)NBUCK * BCAP * sizeof(int2);       // 42.0 MB
    const size_t superBytes = (size_t)NSUPER * SCAP * sizeof(int2);     // 39.7 MB
    const size_t rpBytes  = ((size_t)NTOT + 8) * sizeof(int2);
    const size_t needRadix = 3 * halfMat + 2 * buckBytes + rpBytes + 4096;

    const int spmmBlocks = (NTOT + 3) / 4;

    if (ws_size >= needRadix) {
        // ---- radix path ----
        // [R2: 57.6MB] b0,b1,b2 ; superA (39.7MB) aliases it (dead before init)
        // [R3: 42MB] bucketedB (pass-2 out)  [R1: 42MB] finalE (live all layers)
        char* p = (char*)d_ws;
        __half* b0 = (__half*)p;
        __half* b1 = (__half*)(p + halfMat);
        __half* b2 = (__half*)(p + 2 * halfMat);
        int2* superA = (int2*)d_ws;
        p += 3 * halfMat;
        int2* bucketedB = (int2*)p;          p += buckBytes;
        int2* finalE = (int2*)p;             p += buckBytes;
        int2* rp = (int2*)p;                 p += rpBytes;
        int* cursorS = (int*)p;              // 64 ints
        int* cursorB = cursorS + 64;         // 586 ints

        hipMemsetAsync(cursorS, 0, (64 + NBUCK) * sizeof(int), stream);
        hipLaunchKernelGGL(k_super, dim3((NNZ_E + EPB1 - 1) / EPB1), dim3(256), 0,
                           stream, edge_src, edge_dst, edge_val, cursorS, superA);
        hipLaunchKernelGGL(k_bin, dim3((SCAP + EPB2 - 1) / EPB2, NSUPER), dim3(256),
                           0, stream, superA, cursorS, cursorB, bucketedB);
        hipLaunchKernelGGL(k_sortbucket, dim3(NBUCK), dim3(256), 0, stream,
                           bucketedB, cursorB, finalE, rp);
        hipLaunchKernelGGL(k_init, dim3(2048), dim3(256), 0, stream,
                           user_emb, item_emb, b0);
        hipLaunchKernelGGL((k_spmm_csr<false>), dim3(spmmBlocks), dim3(256), 0,
                           stream, finalE, rp, b0, b1, user_emb, item_emb,
                           (const __half*)nullptr, (const __half*)nullptr, out);
        hipLaunchKernelGGL((k_spmm_csr<false>), dim3(spmmBlocks), dim3(256), 0,
                           stream, finalE, rp, b1, b2, user_emb, item_emb,
                           (const __half*)nullptr, (const __half*)nullptr, out);
        hipLaunchKernelGGL((k_spmm_csr<true>), dim3(spmmBlocks), dim3(256), 0,
                           stream, finalE, rp, b2, (__half*)nullptr, user_emb,
                           item_emb, b1, b2, out);
    } else {
        // ---- fallback: round-9 single-pass path ----
        char* p = (char*)d_ws;
        __half* b0 = (__half*)p;
        __half* b1 = (__half*)(p + halfMat);
        __half* b2 = (__half*)(p + 2 * halfMat);
        int2* bucketedA = (int2*)d_ws;       // alias of b0..b2 (dead before init)
        p += 3 * halfMat;
        int2* bucketedB = (int2*)p;          p += buckBytes;
        int2* rp = (int2*)p;                 p += rpBytes;
        int* cursor = (int*)p;

        hipMemsetAsync(cursor, 0, (size_t)NBUCK * sizeof(int), stream);
        hipLaunchKernelGGL(k_bucket, dim3((NNZ_E + EPB1 - 1) / EPB1), dim3(256), 0,
                           stream, edge_src, edge_dst, edge_val, cursor, bucketedA);
        hipLaunchKernelGGL(k_sortbucket, dim3(NBUCK), dim3(256), 0, stream,
                           bucketedA, cursor, bucketedB, rp);
        hipLaunchKernelGGL(k_init, dim3(2048), dim3(256), 0, stream,
                           user_emb, item_emb, b0);
        hipLaunchKernelGGL((k_spmm_csr<false>), dim3(spmmBlocks), dim3(256), 0,
                           stream, bucketedB, rp, b0, b1, user_emb, item_emb,
                           (const __half*)nullptr, (const __half*)nullptr, out);
        hipLaunchKernelGGL((k_spmm_csr<false>), dim3(spmmBlocks), dim3(256), 0,
                           stream, bucketedB, rp, b1, b2, user_emb, item_emb,
                           (const __half*)nullptr, (const __half*)nullptr, out);
        hipLaunchKernelGGL((k_spmm_csr<true>), dim3(spmmBlocks), dim3(256), 0,
                           stream, bucketedB, rp, b2, (__half*)nullptr, user_emb,
                           item_emb, b1, b2, out);
    }
}

// Round 12
// 499.648 us; speedup vs baseline: 1.0436x; 1.0436x over previous
//
#include <hip/hip_runtime.h>
#include <hip/hip_fp16.h>

#define NUM_USERS 100000
#define NUM_ITEMS 50000
#define NTOT (NUM_USERS + NUM_ITEMS)
#define EMBED_DIM 64
#define NNZ_E 4800000
#define NUM_LAYERS 3

#define ROWS_PER_BUCKET 256
#define NBUCK ((NTOT + ROWS_PER_BUCKET - 1) / ROWS_PER_BUCKET)   // 586
#define BCAP 8960                   // bucket mean 8191 + 8.5 sigma
#define NSUPER 37                   // src >> 12 : 4096 rows per super
#define SCAP 134144                 // super mean 131072 + 8.6 sigma
#define EPB1 4096                   // edges per block, pass 1 (1172 blocks)
#define EPB2 4096                   // edges per block, pass 2
#define DMASK 0x3FFFF               // 18 bits for dst (< 150000 < 2^18)

// ---------------- init: b0(fp16) = concat(user_emb, item_emb) ----------------
__global__ void __launch_bounds__(256)
k_init(const float* __restrict__ ue, const float* __restrict__ ie,
       __half* __restrict__ b0) {
    const long long total2 = (long long)NTOT * EMBED_DIM / 2;
    const long long u2 = (long long)NUM_USERS * EMBED_DIM / 2;
    const float2* ue2 = (const float2*)ue;
    const float2* ie2 = (const float2*)ie;
    __half2* b02 = (__half2*)b0;
    for (long long i = (long long)blockIdx.x * blockDim.x + threadIdx.x;
         i < total2; i += (long long)gridDim.x * blockDim.x) {
        float2 v = (i < u2) ? ue2[i] : ie2[i - u2];
        b02[i] = __floats2half2_rn(v.x, v.y);
    }
}

// ---------------- radix pass 1: bin into 37 supers (int2 payload) ------------
__global__ void __launch_bounds__(256)
k_super(const int* __restrict__ src, const int* __restrict__ dst,
        const float* __restrict__ val, int* __restrict__ cursorS,
        int2* __restrict__ outS) {
    __shared__ int h[NSUPER];
    __shared__ int base[NSUPER];
    int t = threadIdx.x;
    if (t < NSUPER) h[t] = 0;
    __syncthreads();
    long long e0 = (long long)blockIdx.x * EPB1;
    int n = (int)(((long long)NNZ_E - e0) < EPB1 ? (NNZ_E - e0) : EPB1);
    for (int i = t; i < n; i += 256) {
        int s = __builtin_nontemporal_load(&src[e0 + i]);
        atomicAdd(&h[s >> 12], 1);
    }
    __syncthreads();
    if (t < NSUPER) {
        int c = h[t];
        base[t] = (c > 0) ? atomicAdd(&cursorS[t], c) : 0;
        h[t] = 0;
    }
    __syncthreads();
    for (int i = t; i < n; i += 256) {
        int s = __builtin_nontemporal_load(&src[e0 + i]);
        int d = __builtin_nontemporal_load(&dst[e0 + i]);
        float v = __builtin_nontemporal_load(&val[e0 + i]);
        int sb = s >> 12;
        int off = base[sb] + atomicAdd(&h[sb], 1);
        outS[(long long)sb * SCAP + off] =
            make_int2(d | ((s & 4095) << 18), __float_as_int(v));  // 18b dst | 12b row
    }
}

// ---------------- radix pass 2: super -> 16 buckets --------------------------
__global__ void __launch_bounds__(256)
k_bin(const int2* __restrict__ superA, const int* __restrict__ cursorS,
      int* __restrict__ cursorB, int2* __restrict__ outB) {
    __shared__ int h[16];
    __shared__ int base16[16];
    int s = blockIdx.y;
    int cnt = cursorS[s];
    int beg = blockIdx.x * EPB2;
    if (beg >= cnt) return;
    int n = (cnt - beg < EPB2) ? (cnt - beg) : EPB2;
    int t = threadIdx.x;
    const long long* in8 = (const long long*)(superA + (long long)s * SCAP + beg);
    if (t < 16) h[t] = 0;
    __syncthreads();
    for (int i = t; i < n; i += 256) {
        long long raw = __builtin_nontemporal_load(&in8[i]);
        int row12 = ((int)raw >> 18) & 4095;
        atomicAdd(&h[row12 >> 8], 1);
    }
    __syncthreads();
    if (t < 16) {
        int c = h[t];
        base16[t] = (c > 0) ? atomicAdd(&cursorB[s * 16 + t], c) : 0;
        h[t] = 0;
    }
    __syncthreads();
    for (int i = t; i < n; i += 256) {
        long long raw = __builtin_nontemporal_load(&in8[i]);
        int ex = (int)raw;
        int row12 = (ex >> 18) & 4095;
        int bl = row12 >> 8;
        int off = base16[bl] + atomicAdd(&h[bl], 1);
        outB[(long long)(s * 16 + bl) * BCAP + off] =
            make_int2((ex & DMASK) | ((row12 & 255) << 18), (int)(raw >> 32));
    }
}

// ------- phase 3: per-bucket IN-PLACE LDS counting sort -> row-grouped -------
// Whole bucket staged in LDS first, then scattered back to the SAME global
// region (no separate output buffer; no read-after-overwrite hazard).
__global__ void __launch_bounds__(256)
k_sortip(int2* __restrict__ buf, const int* __restrict__ cursor,
         int2* __restrict__ rp) {
    __shared__ int h[ROWS_PER_BUCKET];
    __shared__ int excl[ROWS_PER_BUCKET];
    __shared__ int cur[ROWS_PER_BUCKET];
    __shared__ long long stage[BCAP];     // 71,680 B
    int b = blockIdx.x;
    int t = threadIdx.x;
    int cnt = cursor[b];
    long long gb = (long long)b * BCAP;
    long long* g8 = (long long*)buf + gb;
    h[t] = 0;
    __syncthreads();
    for (int i = t; i < cnt; i += 256) {
        long long raw = __builtin_nontemporal_load(&g8[i]);
        stage[i] = raw;
        atomicAdd(&h[((int)raw >> 18) & 255], 1);
    }
    __syncthreads();
    int v = h[t];
    excl[t] = v;
    __syncthreads();
    for (int off = 1; off < 256; off <<= 1) {
        int x = (t >= off) ? excl[t - off] : 0;
        __syncthreads();
        excl[t] += x;
        __syncthreads();
    }
    int myExcl = excl[t] - v;
    cur[t] = myExcl;
    int row = b * ROWS_PER_BUCKET + t;
    if (row < NTOT) rp[row] = make_int2((int)(gb + myExcl), (int)(gb + myExcl + v));
    __syncthreads();
    for (int i = t; i < cnt; i += 256) {
        long long raw = stage[i];
        int r = ((int)raw >> 18) & 255;
        int slot = atomicAdd(&cur[r], 1);
        g8[slot] = raw;
    }
}

// ---- CSR SpMM: one wave per row, half2 gather (32 lanes/row), 8-wide -------
// LAST layer fuses the final average: out = (eb0 + eb1 + x + acc) / 4
// (x IS the layer-2 output, so no separate b2 pointer — no aliasing).
template <bool LAST>
__global__ void __launch_bounds__(256)
k_spmm_csr(const int2* __restrict__ edges, const int2* __restrict__ rp,
           const __half* __restrict__ x, __half* __restrict__ nxt,
           const __half* __restrict__ eb0, const __half* __restrict__ eb1,
           float* __restrict__ out) {
    int row = blockIdx.x * 4 + (threadIdx.x >> 6);
    int lane = threadIdx.x & 63;
    if (row >= NTOT) return;
    int2 be = rp[row];
    int beg = be.x;
    int end = be.y;
    int sub = lane >> 5;
    int l2 = lane & 31;
    const __half2* x2 = (const __half2*)x;   // row stride 32 half2
    float accx = 0.f, accy = 0.f;
    int j = beg;
    for (; j + 16 <= end; j += 16) {
        int2 e[8];
        __half2 xv[8];
#pragma unroll
        for (int k = 0; k < 8; ++k) e[k] = edges[j + sub * 8 + k];
#pragma unroll
        for (int k = 0; k < 8; ++k)
            xv[k] = x2[(long long)(e[k].x & DMASK) * 32 + l2];
#pragma unroll
        for (int k = 0; k < 8; ++k) {
            float w = __int_as_float(e[k].y);
            float2 xf = __half22float2(xv[k]);
            accx = fmaf(w, xf.x, accx);
            accy = fmaf(w, xf.y, accy);
        }
    }
    for (int t2 = j + sub; t2 < end; t2 += 2) {
        int2 e = edges[t2];
        float w = __int_as_float(e.y);
        float2 xf = __half22float2(x2[(long long)(e.x & DMASK) * 32 + l2]);
        accx = fmaf(w, xf.x, accx);
        accy = fmaf(w, xf.y, accy);
    }
    accx += __shfl_xor(accx, 32);
    accy += __shfl_xor(accy, 32);
    if (sub == 0) {
        if (!LAST) {
            ((__half2*)nxt)[(long long)row * 32 + l2] = __floats2half2_rn(accx, accy);
        } else {
            float2 v  = __half22float2(((const __half2*)eb0)[(long long)row * 32 + l2]);
            float2 a  = __half22float2(((const __half2*)eb1)[(long long)row * 32 + l2]);
            float2 bb = __half22float2(x2[(long long)row * 32 + l2]);
            const float s = 1.0f / (NUM_LAYERS + 1);
            float2 r;
            r.x = (v.x + a.x + bb.x + accx) * s;
            r.y = (v.y + a.y + bb.y + accy) * s;
            ((float2*)out)[(long long)row * 32 + l2] = r;
        }
    }
}

extern "C" void kernel_launch(void* const* d_in, const int* in_sizes, int n_in,
                              void* d_out, int out_size, void* d_ws, size_t ws_size,
                              hipStream_t stream) {
    const float* user_emb = (const float*)d_in[0];
    const float* item_emb = (const float*)d_in[1];
    const int* edge_src   = (const int*)d_in[2];
    const int* edge_dst   = (const int*)d_in[3];
    const float* edge_val = (const float*)d_in[4];
    float* out = (float*)d_out;

    auto al = [](size_t x) { return (x + 255) & ~(size_t)255; };
    const size_t halfMat   = (size_t)NTOT * EMBED_DIM * sizeof(__half);   // 19.2 MB
    const size_t buckBytes = al((size_t)NBUCK * BCAP * sizeof(int2));     // 42.0 MB
    const size_t rpBytes   = al(((size_t)NTOT + 8) * sizeof(int2));

    // layout: [b0 b1 b2 | bucketedB (sorted in place) | rp | cursors]
    // superA (39.7 MB int2) ALIASES b0..b2 start; dead before k_init.
    char* p = (char*)d_ws;
    __half* b0 = (__half*)p;
    __half* b1 = (__half*)(p + halfMat);
    __half* b2 = (__half*)(p + 2 * halfMat);
    int2* superA = (int2*)d_ws;
    p += 3 * halfMat;
    int2* bucketedB = (int2*)p;          p += buckBytes;
    int2* rp = (int2*)p;                 p += rpBytes;
    int* cursorS = (int*)p;              // 64 ints (NSUPER=37 used)
    int* cursorB = cursorS + 64;         // 592 ints (586 used)

    // zero the whole cursor block generously (4 KB)
    hipMemsetAsync(cursorS, 0, 4096, stream);

    // 1. radix pass 1: 37 supers
    hipLaunchKernelGGL(k_super, dim3((NNZ_E + EPB1 - 1) / EPB1), dim3(256), 0,
                       stream, edge_src, edge_dst, edge_val, cursorS, superA);
    // 2. radix pass 2: 16 buckets per super
    hipLaunchKernelGGL(k_bin, dim3((SCAP + EPB2 - 1) / EPB2, NSUPER), dim3(256),
                       0, stream, superA, cursorS, cursorB, bucketedB);
    // 3. per-bucket in-place LDS counting sort -> row-grouped + rp
    hipLaunchKernelGGL(k_sortip, dim3(NBUCK), dim3(256), 0, stream,
                       bucketedB, cursorB, rp);
    // 4. init b0 (fp16 ego); overwrites superA region
    hipLaunchKernelGGL(k_init, dim3(2048), dim3(256), 0, stream,
                       user_emb, item_emb, b0);

    // 5. layers 1..2 write fp16 buffers; layer 3 fuses the final average
    const int spmmBlocks = (NTOT + 3) / 4;
    hipLaunchKernelGGL((k_spmm_csr<false>), dim3(spmmBlocks), dim3(256), 0,
                       stream, bucketedB, rp, b0, b1,
                       (const __half*)nullptr, (const __half*)nullptr, out);
    hipLaunchKernelGGL((k_spmm_csr<false>), dim3(spmmBlocks), dim3(256), 0,
                       stream, bucketedB, rp, b1, b2,
                       (const __half*)nullptr, (const __half*)nullptr, out);
    hipLaunchKernelGGL((k_spmm_csr<true>), dim3(spmmBlocks), dim3(256), 0,
                       stream, bucketedB, rp, b2, (__half*)nullptr,
                       b0, b1, out);
}

// Round 13
// 418.287 us; speedup vs baseline: 1.2466x; 1.1945x over previous
//
#include <hip/hip_runtime.h>
#include <hip/hip_fp16.h>

#define NUM_USERS 100000
#define NUM_ITEMS 50000
#define NTOT (NUM_USERS + NUM_ITEMS)
#define EMBED_DIM 64
#define NNZ_E 4800000
#define NUM_LAYERS 3

#define ROWS_PER_BUCKET 256
#define NBUCK ((NTOT + ROWS_PER_BUCKET - 1) / ROWS_PER_BUCKET)   // 586
#define BCAP 8960                   // bucket mean 8191 + 8.5 sigma
#define NSUPER 37                   // src >> 12 : 4096 rows per super
#define SCAP 134144                 // super mean 131072 + 8.6 sigma
#define EPB1 4096                   // edges per block, pass 1 (1172 blocks)
#define EPB2 4096                   // edges per block, pass 2
#define DMASK 0x3FFFF               // 18 bits for dst (< 150000 < 2^18)

// ---------------- init: b0(fp16) = concat(user_emb, item_emb) ----------------
__global__ void __launch_bounds__(256)
k_init(const float* __restrict__ ue, const float* __restrict__ ie,
       __half* __restrict__ b0) {
    const long long total2 = (long long)NTOT * EMBED_DIM / 2;
    const long long u2 = (long long)NUM_USERS * EMBED_DIM / 2;
    const float2* ue2 = (const float2*)ue;
    const float2* ie2 = (const float2*)ie;
    __half2* b02 = (__half2*)b0;
    for (long long i = (long long)blockIdx.x * blockDim.x + threadIdx.x;
         i < total2; i += (long long)gridDim.x * blockDim.x) {
        float2 v = (i < u2) ? ue2[i] : ie2[i - u2];
        b02[i] = __floats2half2_rn(v.x, v.y);
    }
}

// ---------------- radix pass 1: bin into 37 supers (int2 payload) ------------
__global__ void __launch_bounds__(256)
k_super(const int* __restrict__ src, const int* __restrict__ dst,
        const float* __restrict__ val, int* __restrict__ cursorS,
        int2* __restrict__ outS) {
    __shared__ int h[NSUPER];
    __shared__ int base[NSUPER];
    int t = threadIdx.x;
    if (t < NSUPER) h[t] = 0;
    __syncthreads();
    long long e0 = (long long)blockIdx.x * EPB1;
    int n = (int)(((long long)NNZ_E - e0) < EPB1 ? (NNZ_E - e0) : EPB1);
    for (int i = t; i < n; i += 256) {
        int s = __builtin_nontemporal_load(&src[e0 + i]);
        atomicAdd(&h[s >> 12], 1);
    }
    __syncthreads();
    if (t < NSUPER) {
        int c = h[t];
        base[t] = (c > 0) ? atomicAdd(&cursorS[t], c) : 0;
        h[t] = 0;
    }
    __syncthreads();
    for (int i = t; i < n; i += 256) {
        int s = __builtin_nontemporal_load(&src[e0 + i]);
        int d = __builtin_nontemporal_load(&dst[e0 + i]);
        float v = __builtin_nontemporal_load(&val[e0 + i]);
        int sb = s >> 12;
        int off = base[sb] + atomicAdd(&h[sb], 1);
        outS[(long long)sb * SCAP + off] =
            make_int2(d | ((s & 4095) << 18), __float_as_int(v));  // 18b dst | 12b row
    }
}

// ---------------- radix pass 2: super -> 16 buckets --------------------------
__global__ void __launch_bounds__(256)
k_bin(const int2* __restrict__ superA, const int* __restrict__ cursorS,
      int* __restrict__ cursorB, int2* __restrict__ outB) {
    __shared__ int h[16];
    __shared__ int base16[16];
    int s = blockIdx.y;
    int cnt = cursorS[s];
    int beg = blockIdx.x * EPB2;
    if (beg >= cnt) return;
    int n = (cnt - beg < EPB2) ? (cnt - beg) : EPB2;
    int t = threadIdx.x;
    const long long* in8 = (const long long*)(superA + (long long)s * SCAP + beg);
    if (t < 16) h[t] = 0;
    __syncthreads();
    for (int i = t; i < n; i += 256) {
        long long raw = __builtin_nontemporal_load(&in8[i]);
        int row12 = ((int)raw >> 18) & 4095;
        atomicAdd(&h[row12 >> 8], 1);
    }
    __syncthreads();
    if (t < 16) {
        int c = h[t];
        base16[t] = (c > 0) ? atomicAdd(&cursorB[s * 16 + t], c) : 0;
        h[t] = 0;
    }
    __syncthreads();
    for (int i = t; i < n; i += 256) {
        long long raw = __builtin_nontemporal_load(&in8[i]);
        int ex = (int)raw;
        int row12 = (ex >> 18) & 4095;
        int bl = row12 >> 8;
        int off = base16[bl] + atomicAdd(&h[bl], 1);
        outB[(long long)(s * 16 + bl) * BCAP + off] =
            make_int2((ex & DMASK) | ((row12 & 255) << 18), (int)(raw >> 32));
    }
}

// ------- phase 3: per-bucket IN-PLACE LDS counting sort -> row-grouped -------
__global__ void __launch_bounds__(256)
k_sortip(int2* __restrict__ buf, const int* __restrict__ cursor,
         int2* __restrict__ rp) {
    __shared__ int h[ROWS_PER_BUCKET];
    __shared__ int excl[ROWS_PER_BUCKET];
    __shared__ int cur[ROWS_PER_BUCKET];
    __shared__ long long stage[BCAP];     // 71,680 B
    int b = blockIdx.x;
    int t = threadIdx.x;
    int cnt = cursor[b];
    long long gb = (long long)b * BCAP;
    long long* g8 = (long long*)buf + gb;
    h[t] = 0;
    __syncthreads();
    for (int i = t; i < cnt; i += 256) {
        long long raw = __builtin_nontemporal_load(&g8[i]);
        stage[i] = raw;
        atomicAdd(&h[((int)raw >> 18) & 255], 1);
    }
    __syncthreads();
    int v = h[t];
    excl[t] = v;
    __syncthreads();
    for (int off = 1; off < 256; off <<= 1) {
        int x = (t >= off) ? excl[t - off] : 0;
        __syncthreads();
        excl[t] += x;
        __syncthreads();
    }
    int myExcl = excl[t] - v;
    cur[t] = myExcl;
    int row = b * ROWS_PER_BUCKET + t;
    if (row < NTOT) rp[row] = make_int2((int)(gb + myExcl), (int)(gb + myExcl + v));
    __syncthreads();
    for (int i = t; i < cnt; i += 256) {
        long long raw = stage[i];
        int r = ((int)raw >> 18) & 255;
        int slot = atomicAdd(&cur[r], 1);
        g8[slot] = raw;
    }
}

// ---- helpers for the 16-lane-row SpMM --------------------------------------
__device__ __forceinline__ void unpack4(float2 p, float& x0, float& x1,
                                        float& x2, float& x3) {
    __half2 h01 = *(const __half2*)&p.x;
    __half2 h23 = *(const __half2*)&p.y;
    float2 f01 = __half22float2(h01);
    float2 f23 = __half22float2(h23);
    x0 = f01.x; x1 = f01.y; x2 = f23.x; x3 = f23.y;
}

// group-gather: 4*U edges at j; 16-lane group `grp` handles U of them
template <int U>
__device__ __forceinline__ void gg(const int2* __restrict__ edges, int j, int grp,
                                   int l16, const float2* __restrict__ xq,
                                   float& a0, float& a1, float& a2, float& a3) {
    int2 e[U];
    float2 xv[U];
#pragma unroll
    for (int k = 0; k < U; ++k) e[k] = edges[j + grp * U + k];
#pragma unroll
    for (int k = 0; k < U; ++k)
        xv[k] = xq[(long long)(e[k].x & DMASK) * 16 + l16];
#pragma unroll
    for (int k = 0; k < U; ++k) {
        float w = __int_as_float(e[k].y);
        float x0, x1, x2, x3;
        unpack4(xv[k], x0, x1, x2, x3);
        a0 = fmaf(w, x0, a0);
        a1 = fmaf(w, x1, a1);
        a2 = fmaf(w, x2, a2);
        a3 = fmaf(w, x3, a3);
    }
}

// ---- CSR SpMM: one wave per row, 16 lanes/row x 4 edge-groups --------------
// 32 cache lines in flight per wave in the main tier (4 groups x 8 unroll).
// LAST layer fuses the final average: out = (eb0 + eb1 + x + acc) / 4.
template <bool LAST>
__global__ void __launch_bounds__(256)
k_spmm_csr(const int2* __restrict__ edges, const int2* __restrict__ rp,
           const __half* __restrict__ x, __half* __restrict__ nxt,
           const __half* __restrict__ eb0, const __half* __restrict__ eb1,
           float* __restrict__ out) {
    int row = blockIdx.x * 4 + (threadIdx.x >> 6);
    int lane = threadIdx.x & 63;
    if (row >= NTOT) return;
    int2 be = rp[row];
    int beg = be.x;
    int end = be.y;
    int grp = lane >> 4;     // 0..3
    int l16 = lane & 15;
    const float2* xq = (const float2*)x;   // row stride 16 float2 (128 B)
    float a0 = 0.f, a1 = 0.f, a2 = 0.f, a3 = 0.f;
    int j = beg;
    for (; j + 32 <= end; j += 32) gg<8>(edges, j, grp, l16, xq, a0, a1, a2, a3);
    if (j + 16 <= end) { gg<4>(edges, j, grp, l16, xq, a0, a1, a2, a3); j += 16; }
    if (j + 8 <= end)  { gg<2>(edges, j, grp, l16, xq, a0, a1, a2, a3); j += 8; }
    for (int t2 = j + grp; t2 < end; t2 += 4) {
        int2 e = edges[t2];
        float w = __int_as_float(e.y);
        float x0, x1, x2, x3;
        unpack4(xq[(long long)(e.x & DMASK) * 16 + l16], x0, x1, x2, x3);
        a0 = fmaf(w, x0, a0);
        a1 = fmaf(w, x1, a1);
        a2 = fmaf(w, x2, a2);
        a3 = fmaf(w, x3, a3);
    }
    // combine the 4 groups
    a0 += __shfl_xor(a0, 16); a1 += __shfl_xor(a1, 16);
    a2 += __shfl_xor(a2, 16); a3 += __shfl_xor(a3, 16);
    a0 += __shfl_xor(a0, 32); a1 += __shfl_xor(a1, 32);
    a2 += __shfl_xor(a2, 32); a3 += __shfl_xor(a3, 32);
    if (grp == 0) {
        if (!LAST) {
            union { __half2 h[2]; float2 f; } u;
            u.h[0] = __floats2half2_rn(a0, a1);
            u.h[1] = __floats2half2_rn(a2, a3);
            ((float2*)nxt)[(long long)row * 16 + l16] = u.f;
        } else {
            float v0, v1, v2, v3, w0, w1, w2, w3, z0, z1, z2, z3;
            unpack4(((const float2*)eb0)[(long long)row * 16 + l16], v0, v1, v2, v3);
            unpack4(((const float2*)eb1)[(long long)row * 16 + l16], w0, w1, w2, w3);
            unpack4(xq[(long long)row * 16 + l16], z0, z1, z2, z3);
            const float s = 1.0f / (NUM_LAYERS + 1);
            float4 r;
            r.x = (v0 + w0 + z0 + a0) * s;
            r.y = (v1 + w1 + z1 + a1) * s;
            r.z = (v2 + w2 + z2 + a2) * s;
            r.w = (v3 + w3 + z3 + a3) * s;
            ((float4*)out)[(long long)row * 16 + l16] = r;
        }
    }
}

extern "C" void kernel_launch(void* const* d_in, const int* in_sizes, int n_in,
                              void* d_out, int out_size, void* d_ws, size_t ws_size,
                              hipStream_t stream) {
    const float* user_emb = (const float*)d_in[0];
    const float* item_emb = (const float*)d_in[1];
    const int* edge_src   = (const int*)d_in[2];
    const int* edge_dst   = (const int*)d_in[3];
    const float* edge_val = (const float*)d_in[4];
    float* out = (float*)d_out;

    auto al = [](size_t x) { return (x + 255) & ~(size_t)255; };
    const size_t halfMat   = (size_t)NTOT * EMBED_DIM * sizeof(__half);   // 19.2 MB
    const size_t buckBytes = al((size_t)NBUCK * BCAP * sizeof(int2));     // 42.0 MB
    const size_t rpBytes   = al(((size_t)NTOT + 8) * sizeof(int2));

    // layout: [b0 b1 b2 | bucketedB (sorted in place) | rp | cursors]
    // superA (39.7 MB int2) ALIASES b0..b2 start; dead before k_init.
    char* p = (char*)d_ws;
    __half* b0 = (__half*)p;
    __half* b1 = (__half*)(p + halfMat);
    __half* b2 = (__half*)(p + 2 * halfMat);
    int2* superA = (int2*)d_ws;
    p += 3 * halfMat;
    int2* bucketedB = (int2*)p;          p += buckBytes;
    int2* rp = (int2*)p;                 p += rpBytes;
    int* cursorS = (int*)p;              // 64 ints (NSUPER=37 used)
    int* cursorB = cursorS + 64;         // 592 ints (586 used)

    hipMemsetAsync(cursorS, 0, 4096, stream);

    // 1. radix pass 1: 37 supers
    hipLaunchKernelGGL(k_super, dim3((NNZ_E + EPB1 - 1) / EPB1), dim3(256), 0,
                       stream, edge_src, edge_dst, edge_val, cursorS, superA);
    // 2. radix pass 2: 16 buckets per super
    hipLaunchKernelGGL(k_bin, dim3((SCAP + EPB2 - 1) / EPB2, NSUPER), dim3(256),
                       0, stream, superA, cursorS, cursorB, bucketedB);
    // 3. per-bucket in-place LDS counting sort -> row-grouped + rp
    hipLaunchKernelGGL(k_sortip, dim3(NBUCK), dim3(256), 0, stream,
                       bucketedB, cursorB, rp);
    // 4. init b0 (fp16 ego); overwrites superA region
    hipLaunchKernelGGL(k_init, dim3(2048), dim3(256), 0, stream,
                       user_emb, item_emb, b0);

    // 5. layers 1..2 write fp16 buffers; layer 3 fuses the final average
    const int spmmBlocks = (NTOT + 3) / 4;
    hipLaunchKernelGGL((k_spmm_csr<false>), dim3(spmmBlocks), dim3(256), 0,
                       stream, bucketedB, rp, b0, b1,
                       (const __half*)nullptr, (const __half*)nullptr, out);
    hipLaunchKernelGGL((k_spmm_csr<false>), dim3(spmmBlocks), dim3(256), 0,
                       stream, bucketedB, rp, b1, b2,
                       (const __half*)nullptr, (const __half*)nullptr, out);
    hipLaunchKernelGGL((k_spmm_csr<true>), dim3(spmmBlocks), dim3(256), 0,
                       stream, bucketedB, rp, b2, (__half*)nullptr,
                       b0, b1, out);
}

// Round 14
// 410.052 us; speedup vs baseline: 1.2716x; 1.0201x over previous
//
#include <hip/hip_runtime.h>
#include <hip/hip_fp16.h>

#define NUM_USERS 100000
#define NUM_ITEMS 50000
#define NTOT (NUM_USERS + NUM_ITEMS)
#define EMBED_DIM 64
#define NNZ_E 4800000
#define NUM_LAYERS 3

#define RPB 128                     // rows per bucket
#define NBUCK ((NTOT + RPB - 1) / RPB)          // 1172
#define BCAP 4672                   // bucket mean 4096 + 9 sigma (64)
#define NSUPER 37                   // src >> 12 : 4096 rows per super
#define SCAP 134144                 // super mean 131072 + 8.6 sigma
#define EPB1 4096                   // edges per block, pass 1 (1172 blocks)
#define EPB2 4096                   // edges per block, pass 2
#define DMASK 0x3FFFF               // 18 bits for dst (< 150000 < 2^18)

// ---------------- init: b0(fp16) = concat(user_emb, item_emb) ----------------
__global__ void __launch_bounds__(256)
k_init(const float* __restrict__ ue, const float* __restrict__ ie,
       __half* __restrict__ b0) {
    const long long total2 = (long long)NTOT * EMBED_DIM / 2;
    const long long u2 = (long long)NUM_USERS * EMBED_DIM / 2;
    const float2* ue2 = (const float2*)ue;
    const float2* ie2 = (const float2*)ie;
    __half2* b02 = (__half2*)b0;
    for (long long i = (long long)blockIdx.x * blockDim.x + threadIdx.x;
         i < total2; i += (long long)gridDim.x * blockDim.x) {
        float2 v = (i < u2) ? ue2[i] : ie2[i - u2];
        b02[i] = __floats2half2_rn(v.x, v.y);
    }
}

// ------- radix pass 1: bin into 37 supers (src cached in LDS, read once) -----
__global__ void __launch_bounds__(256)
k_super(const int* __restrict__ src, const int* __restrict__ dst,
        const float* __restrict__ val, int* __restrict__ cursorS,
        int2* __restrict__ outS) {
    __shared__ int h[NSUPER];
    __shared__ int base[NSUPER];
    __shared__ int srcbuf[EPB1];     // 16 KB
    int t = threadIdx.x;
    if (t < NSUPER) h[t] = 0;
    __syncthreads();
    long long e0 = (long long)blockIdx.x * EPB1;
    int n = (int)(((long long)NNZ_E - e0) < EPB1 ? (NNZ_E - e0) : EPB1);
    for (int i = t; i < n; i += 256) {
        int s = __builtin_nontemporal_load(&src[e0 + i]);
        srcbuf[i] = s;
        atomicAdd(&h[s >> 12], 1);
    }
    __syncthreads();
    if (t < NSUPER) {
        int c = h[t];
        base[t] = (c > 0) ? atomicAdd(&cursorS[t], c) : 0;
        h[t] = 0;
    }
    __syncthreads();
    for (int i = t; i < n; i += 256) {
        int s = srcbuf[i];
        int d = __builtin_nontemporal_load(&dst[e0 + i]);
        float v = __builtin_nontemporal_load(&val[e0 + i]);
        int sb = s >> 12;
        int off = base[sb] + atomicAdd(&h[sb], 1);
        outS[(long long)sb * SCAP + off] =
            make_int2(d | ((s & 4095) << 18), __float_as_int(v));  // 18b dst | 12b row
    }
}

// ---------------- radix pass 2: super -> 32 buckets of 128 rows --------------
__global__ void __launch_bounds__(256)
k_bin(const int2* __restrict__ superA, const int* __restrict__ cursorS,
      int* __restrict__ cursorB, int2* __restrict__ outB) {
    __shared__ int h[32];
    __shared__ int base32[32];
    int s = blockIdx.y;
    int cnt = cursorS[s];
    int beg = blockIdx.x * EPB2;
    if (beg >= cnt) return;
    int n = (cnt - beg < EPB2) ? (cnt - beg) : EPB2;
    int t = threadIdx.x;
    const long long* in8 = (const long long*)(superA + (long long)s * SCAP + beg);
    if (t < 32) h[t] = 0;
    __syncthreads();
    for (int i = t; i < n; i += 256) {
        long long raw = __builtin_nontemporal_load(&in8[i]);
        int row12 = ((int)raw >> 18) & 4095;
        atomicAdd(&h[row12 >> 7], 1);
    }
    __syncthreads();
    if (t < 32) {
        int c = h[t];
        base32[t] = (c > 0) ? atomicAdd(&cursorB[s * 32 + t], c) : 0;
        h[t] = 0;
    }
    __syncthreads();
    for (int i = t; i < n; i += 256) {
        long long raw = __builtin_nontemporal_load(&in8[i]);
        int ex = (int)raw;
        int row12 = (ex >> 18) & 4095;
        int bl = row12 >> 7;
        int off = base32[bl] + atomicAdd(&h[bl], 1);
        outB[(long long)(s * 32 + bl) * BCAP + off] =
            make_int2((ex & DMASK) | ((row12 & 127) << 18), (int)(raw >> 32));
    }
}

// ------- phase 3: per-bucket IN-PLACE LDS counting sort (512 thr, 4 blk/CU) --
__global__ void __launch_bounds__(512)
k_sortip(int2* __restrict__ buf, const int* __restrict__ cursor,
         int2* __restrict__ rp) {
    __shared__ int h[RPB];
    __shared__ int excl[RPB];
    __shared__ int cur[RPB];
    __shared__ long long stage[BCAP];     // 37,376 B
    int b = blockIdx.x;
    int t = threadIdx.x;
    int cnt = cursor[b];
    long long gb = (long long)b * BCAP;
    long long* g8 = (long long*)buf + gb;
    if (t < RPB) h[t] = 0;
    __syncthreads();
    for (int i = t; i < cnt; i += 512) {
        long long raw = __builtin_nontemporal_load(&g8[i]);
        stage[i] = raw;
        atomicAdd(&h[((int)raw >> 18) & 127], 1);
    }
    __syncthreads();
    int v = 0;
    if (t < RPB) { v = h[t]; excl[t] = v; }
    __syncthreads();
    for (int off = 1; off < RPB; off <<= 1) {
        int x = 0;
        if (t < RPB && t >= off) x = excl[t - off];
        __syncthreads();
        if (t < RPB) excl[t] += x;
        __syncthreads();
    }
    if (t < RPB) {
        int myExcl = excl[t] - v;
        cur[t] = myExcl;
        int row = b * RPB + t;
        if (row < NTOT)
            rp[row] = make_int2((int)(gb + myExcl), (int)(gb + myExcl + v));
    }
    __syncthreads();
    for (int i = t; i < cnt; i += 512) {
        long long raw = stage[i];
        int r = ((int)raw >> 18) & 127;
        int slot = atomicAdd(&cur[r], 1);
        g8[slot] = raw;
    }
}

// ---- helpers for the 16-lane-row SpMM --------------------------------------
__device__ __forceinline__ void unpack4(float2 p, float& x0, float& x1,
                                        float& x2, float& x3) {
    __half2 h01 = *(const __half2*)&p.x;
    __half2 h23 = *(const __half2*)&p.y;
    float2 f01 = __half22float2(h01);
    float2 f23 = __half22float2(h23);
    x0 = f01.x; x1 = f01.y; x2 = f23.x; x3 = f23.y;
}

// group-gather: 4*U edges at j; 16-lane group `grp` handles U of them
template <int U>
__device__ __forceinline__ void gg(const int2* __restrict__ edges, int j, int grp,
                                   int l16, const float2* __restrict__ xq,
                                   float& a0, float& a1, float& a2, float& a3) {
    int2 e[U];
    float2 xv[U];
#pragma unroll
    for (int k = 0; k < U; ++k) e[k] = edges[j + grp * U + k];
#pragma unroll
    for (int k = 0; k < U; ++k)
        xv[k] = xq[(long long)(e[k].x & DMASK) * 16 + l16];
#pragma unroll
    for (int k = 0; k < U; ++k) {
        float w = __int_as_float(e[k].y);
        float x0, x1, x2, x3;
        unpack4(xv[k], x0, x1, x2, x3);
        a0 = fmaf(w, x0, a0);
        a1 = fmaf(w, x1, a1);
        a2 = fmaf(w, x2, a2);
        a3 = fmaf(w, x3, a3);
    }
}

// ---- CSR SpMM: one wave per row, 16 lanes/row x 4 edge-groups --------------
// LAST layer fuses the final average: out = (eb0 + eb1 + x + acc) / 4.
template <bool LAST>
__global__ void __launch_bounds__(256)
k_spmm_csr(const int2* __restrict__ edges, const int2* __restrict__ rp,
           const __half* __restrict__ x, __half* __restrict__ nxt,
           const __half* __restrict__ eb0, const __half* __restrict__ eb1,
           float* __restrict__ out) {
    int row = blockIdx.x * 4 + (threadIdx.x >> 6);
    int lane = threadIdx.x & 63;
    if (row >= NTOT) return;
    int2 be = rp[row];
    int beg = be.x;
    int end = be.y;
    int grp = lane >> 4;     // 0..3
    int l16 = lane & 15;
    const float2* xq = (const float2*)x;   // row stride 16 float2 (128 B)
    float a0 = 0.f, a1 = 0.f, a2 = 0.f, a3 = 0.f;
    int j = beg;
    for (; j + 32 <= end; j += 32) gg<8>(edges, j, grp, l16, xq, a0, a1, a2, a3);
    if (j + 16 <= end) { gg<4>(edges, j, grp, l16, xq, a0, a1, a2, a3); j += 16; }
    if (j + 8 <= end)  { gg<2>(edges, j, grp, l16, xq, a0, a1, a2, a3); j += 8; }
    for (int t2 = j + grp; t2 < end; t2 += 4) {
        int2 e = edges[t2];
        float w = __int_as_float(e.y);
        float x0, x1, x2, x3;
        unpack4(xq[(long long)(e.x & DMASK) * 16 + l16], x0, x1, x2, x3);
        a0 = fmaf(w, x0, a0);
        a1 = fmaf(w, x1, a1);
        a2 = fmaf(w, x2, a2);
        a3 = fmaf(w, x3, a3);
    }
    a0 += __shfl_xor(a0, 16); a1 += __shfl_xor(a1, 16);
    a2 += __shfl_xor(a2, 16); a3 += __shfl_xor(a3, 16);
    a0 += __shfl_xor(a0, 32); a1 += __shfl_xor(a1, 32);
    a2 += __shfl_xor(a2, 32); a3 += __shfl_xor(a3, 32);
    if (grp == 0) {
        if (!LAST) {
            union { __half2 h[2]; float2 f; } u;
            u.h[0] = __floats2half2_rn(a0, a1);
            u.h[1] = __floats2half2_rn(a2, a3);
            ((float2*)nxt)[(long long)row * 16 + l16] = u.f;
        } else {
            float v0, v1, v2, v3, w0, w1, w2, w3, z0, z1, z2, z3;
            unpack4(((const float2*)eb0)[(long long)row * 16 + l16], v0, v1, v2, v3);
            unpack4(((const float2*)eb1)[(long long)row * 16 + l16], w0, w1, w2, w3);
            unpack4(xq[(long long)row * 16 + l16], z0, z1, z2, z3);
            const float s = 1.0f / (NUM_LAYERS + 1);
            float4 r;
            r.x = (v0 + w0 + z0 + a0) * s;
            r.y = (v1 + w1 + z1 + a1) * s;
            r.z = (v2 + w2 + z2 + a2) * s;
            r.w = (v3 + w3 + z3 + a3) * s;
            ((float4*)out)[(long long)row * 16 + l16] = r;
        }
    }
}

extern "C" void kernel_launch(void* const* d_in, const int* in_sizes, int n_in,
                              void* d_out, int out_size, void* d_ws, size_t ws_size,
                              hipStream_t stream) {
    const float* user_emb = (const float*)d_in[0];
    const float* item_emb = (const float*)d_in[1];
    const int* edge_src   = (const int*)d_in[2];
    const int* edge_dst   = (const int*)d_in[3];
    const float* edge_val = (const float*)d_in[4];
    float* out = (float*)d_out;

    auto al = [](size_t x) { return (x + 255) & ~(size_t)255; };
    const size_t halfMat   = (size_t)NTOT * EMBED_DIM * sizeof(__half);   // 19.2 MB
    const size_t buckBytes = al((size_t)NBUCK * BCAP * sizeof(int2));     // 43.8 MB
    const size_t rpBytes   = al(((size_t)NTOT + 8) * sizeof(int2));

    // layout: [b0 b1 b2 | bucketedB (sorted in place) | rp | cursors]
    // superA (39.7 MB int2) ALIASES b0..b2 start; dead before k_init.
    char* p = (char*)d_ws;
    __half* b0 = (__half*)p;
    __half* b1 = (__half*)(p + halfMat);
    __half* b2 = (__half*)(p + 2 * halfMat);
    int2* superA = (int2*)d_ws;
    p += 3 * halfMat;
    int2* bucketedB = (int2*)p;          p += buckBytes;
    int2* rp = (int2*)p;                 p += rpBytes;
    int* cursorS = (int*)p;              // 64 ints (NSUPER=37 used)
    int* cursorB = cursorS + 64;         // 1184 ints (37*32 used)

    // zero cursors (64 + 1184 ints = 4992 B)
    hipMemsetAsync(cursorS, 0, 8192, stream);

    // 1. radix pass 1: 37 supers
    hipLaunchKernelGGL(k_super, dim3((NNZ_E + EPB1 - 1) / EPB1), dim3(256), 0,
                       stream, edge_src, edge_dst, edge_val, cursorS, superA);
    // 2. radix pass 2: 32 buckets of 128 rows per super
    hipLaunchKernelGGL(k_bin, dim3((SCAP + EPB2 - 1) / EPB2, NSUPER), dim3(256),
                       0, stream, superA, cursorS, cursorB, bucketedB);
    // 3. per-bucket in-place LDS counting sort -> row-grouped + rp
    hipLaunchKernelGGL(k_sortip, dim3(NBUCK), dim3(512), 0, stream,
                       bucketedB, cursorB, rp);
    // 4. init b0 (fp16 ego); overwrites superA region
    hipLaunchKernelGGL(k_init, dim3(2048), dim3(256), 0, stream,
                       user_emb, item_emb, b0);

    // 5. layers 1..2 write fp16 buffers; layer 3 fuses the final average
    const int spmmBlocks = (NTOT + 3) / 4;
    hipLaunchKernelGGL((k_spmm_csr<false>), dim3(spmmBlocks), dim3(256), 0,
                       stream, bucketedB, rp, b0, b1,
                       (const __half*)nullptr, (const __half*)nullptr, out);
    hipLaunchKernelGGL((k_spmm_csr<false>), dim3(spmmBlocks), dim3(256), 0,
                       stream, bucketedB, rp, b1, b2,
                       (const __half*)nullptr, (const __half*)nullptr, out);
    hipLaunchKernelGGL((k_spmm_csr<true>), dim3(spmmBlocks), dim3(256), 0,
                       stream, bucketedB, rp, b2, (__half*)nullptr,
                       b0, b1, out);
}